// Round 8
// baseline (5436.717 us; speedup 1.0000x reference)
//
#include <hip/hip_runtime.h>
#include <hip/hip_bf16.h>
#include <math.h>

#define NN 20000
#define NE 640000
#define H  128
#define RB 50
#define NL 6
#define NPB 4   // nodes owned per edge-block (avg 4*32 = 128 edges)

typedef unsigned short u16;
typedef __attribute__((ext_vector_type(8))) short short8v;
typedef __attribute__((ext_vector_type(4))) float f32x4;

__device__ __forceinline__ u16 f2b(float v) {
  unsigned x = __float_as_uint(v);
  unsigned r = (x + 0x7FFFu + ((x >> 16) & 1u)) >> 16;
  return (u16)r;
}
__device__ __forceinline__ float b2f(u16 u) {
  return __uint_as_float(((unsigned int)u) << 16);
}

// ---------------- sort machinery ----------------
__global__ void k_zero_i32(int* __restrict__ p, int n) {
  int i = blockIdx.x * blockDim.x + threadIdx.x;
  if (i < n) p[i] = 0;
}
__global__ void k_hist(const int* __restrict__ ei, int* __restrict__ counts) {
  int e = blockIdx.x * blockDim.x + threadIdx.x;
  if (e < NE) atomicAdd(&counts[ei[NE + e]], 1);
}
// exclusive scan -> starts[0..NN] (starts[NN]=NE) and a mutable copy in cursor
__global__ void k_scan(const int* __restrict__ counts, int* __restrict__ starts,
                       int* __restrict__ cursor) {
  __shared__ int buf[1024];
  __shared__ int carry;
  int tid = threadIdx.x;
  if (tid == 0) carry = 0;
  __syncthreads();
  for (int base = 0; base < NN; base += 1024) {
    int i = base + tid;
    int v = (i < NN) ? counts[i] : 0;
    buf[tid] = v;
    __syncthreads();
    for (int off = 1; off < 1024; off <<= 1) {
      int t = (tid >= off) ? buf[tid - off] : 0;
      __syncthreads();
      buf[tid] += t;
      __syncthreads();
    }
    int incl = buf[tid];
    int excl = incl - v + carry;
    if (i < NN) { starts[i] = excl; cursor[i] = excl; }
    __syncthreads();
    if (tid == 1023) carry += incl;
    __syncthreads();
  }
  if (tid == 0) starts[NN] = NE;
}
__global__ void k_place(const int* __restrict__ ei, int* __restrict__ cursor,
                        int* __restrict__ perm) {
  int e = blockIdx.x * blockDim.x + threadIdx.x;
  if (e < NE) {
    int d = ei[NE + e];
    int p = atomicAdd(&cursor[d], 1);
    perm[p] = e;
  }
}

// ---------------- edge precompute: sorted meta + bf16 RBF features [E][64] ----------------
__global__ void k_edge(const int* __restrict__ ei, const int* __restrict__ perm,
                       const float* __restrict__ pos, const float* __restrict__ means,
                       const float* __restrict__ betas,
                       int* __restrict__ srcS, int* __restrict__ dstS,
                       float* __restrict__ CS, u16* __restrict__ attrG) {
  int p = blockIdx.x * 256 + threadIdx.x;
  if (p >= NE) return;
  int e = perm[p];
  int s = ei[e], t = ei[NE + e];
  srcS[p] = s; dstS[p] = t;
  float dx = pos[3*s]   - pos[3*t];
  float dy = pos[3*s+1] - pos[3*t+1];
  float dz = pos[3*s+2] - pos[3*t+2];
  float d = sqrtf(dx*dx + dy*dy + dz*dz);
  float C = 0.5f * (cosf(d * 0.628318530717958647692f) + 1.0f);
  if (d >= 5.0f) C = 0.f;
  CS[p] = C;
  float tv = expf(-d);
  u16* row = attrG + (size_t)p * 64;
  for (int k = 0; k < RB; ++k) {
    float diff = tv - means[k];
    row[k] = f2b(C * expf(-betas[k] * diff * diff));
  }
  for (int k = RB; k < 64; ++k) row[k] = 0;
}

// ---------------- weight pre-transpose/convert to bf16 ----------------
__global__ void k_prepw(const float* __restrict__ npW, const float* __restrict__ W1,
                        const float* __restrict__ W2, u16* __restrict__ npWt,
                        u16* __restrict__ w1tA, u16* __restrict__ w2tA) {
  int i = blockIdx.x * 256 + threadIdx.x;
  if (i < 8192) {
    int n = i >> 6, k = i & 63;
    npWt[i] = (k < RB) ? f2b(npW[k * H + n]) : (u16)0;
  } else if (i < 57344) {
    int j = i - 8192;
    int l = j >> 13, r = j & 8191;
    int n = r >> 6, k = r & 63;
    w1tA[j] = (k < RB) ? f2b(W1[(size_t)l * RB * H + (size_t)k * H + n]) : (u16)0;
  } else if (i < 161792) {
    int j = i - 57344;
    int l = j / 17408, r = j % 17408;
    int n = r / 136, k = r % 136;
    w2tA[j] = (k < H) ? f2b(W2[(size_t)l * H * H + (size_t)k * H + n]) : (u16)0;
  }
}

__global__ void k_embed(const int* __restrict__ z, const float* __restrict__ emb,
                        const float* __restrict__ nemb,
                        float* __restrict__ x, float* __restrict__ xn) {
  int i = blockIdx.x * blockDim.x + threadIdx.x;
  if (i >= NN * H) return;
  int n = i >> 7, c = i & (H - 1);
  long o = (long)z[n] * H + c;
  x[i]  = emb[o];
  xn[i] = nemb[o];
}

__global__ void k_out(const float* __restrict__ x, float* __restrict__ out) {
  int i = blockIdx.x * blockDim.x + threadIdx.x;
  if (i < NN * H) out[i] = x[i];
}

// ---------------- node GEMM, M-tile 32 ----------------
__global__ __launch_bounds__(256) void k_gemm32(
    const float* __restrict__ A, const float* __restrict__ W,
    const float* __restrict__ bias, const float* __restrict__ add,
    float* __restrict__ out, int useAct)
{
  __shared__ float sA[32][132];
  int tid = threadIdx.x;
  int n0 = blockIdx.x * 32;
  #pragma unroll
  for (int j = 0; j < 4; ++j) {
    int f4 = tid + j * 256;
    int r = f4 >> 5, c4 = f4 & 31;
    *(float4*)&sA[r][c4 * 4] = *(const float4*)&A[(size_t)(n0 + r) * H + c4 * 4];
  }
  __syncthreads();
  int g = tid >> 5;
  int c0 = (tid & 31) * 4;
  int eb = g * 4;
  float acc[4][4];
  #pragma unroll
  for (int i = 0; i < 4; ++i)
    for (int j = 0; j < 4; ++j) acc[i][j] = 0.f;
  for (int k = 0; k < H; ++k) {
    float4 wv = *(const float4*)&W[(size_t)k * H + c0];
    #pragma unroll
    for (int i = 0; i < 4; ++i) {
      float a = sA[eb + i][k];
      acc[i][0] += a * wv.x; acc[i][1] += a * wv.y;
      acc[i][2] += a * wv.z; acc[i][3] += a * wv.w;
    }
  }
  float bv[4] = {0.f, 0.f, 0.f, 0.f};
  if (bias) {
    float4 b4 = *(const float4*)&bias[c0];
    bv[0] = b4.x; bv[1] = b4.y; bv[2] = b4.z; bv[3] = b4.w;
  }
  #pragma unroll
  for (int i = 0; i < 4; ++i) {
    int n = n0 + eb + i;
    float o[4];
    #pragma unroll
    for (int j = 0; j < 4; ++j) {
      float v = acc[i][j] + bv[j];
      if (useAct) v = v / (1.f + __expf(-v));
      o[j] = v;
    }
    if (add) {
      float4 a4 = *(const float4*)&add[(size_t)n * H + c0];
      o[0] += a4.x; o[1] += a4.y; o[2] += a4.z; o[3] += a4.w;
    }
    *(float4*)&out[(size_t)n * H + c0] = make_float4(o[0], o[1], o[2], o[3]);
  }
}

// ---------------- fused lin2+lin: x = x + (silu(A@W2+b2))@W3 + b3 ----------------
__global__ __launch_bounds__(256) void k_gemmF(
    const float* __restrict__ A, const float* __restrict__ W2,
    const float* __restrict__ b2, const float* __restrict__ W3,
    const float* __restrict__ b3, float* __restrict__ x)
{
  __shared__ float sA[32][132];
  __shared__ float sT[32][132];
  int tid = threadIdx.x;
  int n0 = blockIdx.x * 32;
  #pragma unroll
  for (int j = 0; j < 4; ++j) {
    int f4 = tid + j * 256;
    int r = f4 >> 5, c4 = f4 & 31;
    *(float4*)&sA[r][c4 * 4] = *(const float4*)&A[(size_t)(n0 + r) * H + c4 * 4];
  }
  __syncthreads();
  int g = tid >> 5;
  int c0 = (tid & 31) * 4;
  int eb = g * 4;
  float acc[4][4];
  #pragma unroll
  for (int i = 0; i < 4; ++i)
    for (int j = 0; j < 4; ++j) acc[i][j] = 0.f;
  for (int k = 0; k < H; ++k) {
    float4 wv = *(const float4*)&W2[(size_t)k * H + c0];
    #pragma unroll
    for (int i = 0; i < 4; ++i) {
      float a = sA[eb + i][k];
      acc[i][0] += a * wv.x; acc[i][1] += a * wv.y;
      acc[i][2] += a * wv.z; acc[i][3] += a * wv.w;
    }
  }
  float4 bv2 = *(const float4*)&b2[c0];
  #pragma unroll
  for (int i = 0; i < 4; ++i) {
    float t0 = acc[i][0] + bv2.x, t1 = acc[i][1] + bv2.y;
    float t2 = acc[i][2] + bv2.z, t3 = acc[i][3] + bv2.w;
    sT[eb + i][c0 + 0] = t0 / (1.f + __expf(-t0));
    sT[eb + i][c0 + 1] = t1 / (1.f + __expf(-t1));
    sT[eb + i][c0 + 2] = t2 / (1.f + __expf(-t2));
    sT[eb + i][c0 + 3] = t3 / (1.f + __expf(-t3));
  }
  __syncthreads();
  #pragma unroll
  for (int i = 0; i < 4; ++i)
    for (int j = 0; j < 4; ++j) acc[i][j] = 0.f;
  for (int k = 0; k < H; ++k) {
    float4 wv = *(const float4*)&W3[(size_t)k * H + c0];
    #pragma unroll
    for (int i = 0; i < 4; ++i) {
      float a = sT[eb + i][k];
      acc[i][0] += a * wv.x; acc[i][1] += a * wv.y;
      acc[i][2] += a * wv.z; acc[i][3] += a * wv.w;
    }
  }
  float4 bv3 = *(const float4*)&b3[c0];
  #pragma unroll
  for (int i = 0; i < 4; ++i) {
    int n = n0 + eb + i;
    float4 xv = *(const float4*)&x[(size_t)n * H + c0];
    xv.x += acc[i][0] + bv3.x; xv.y += acc[i][1] + bv3.y;
    xv.z += acc[i][2] + bv3.z; xv.w += acc[i][3] + bv3.w;
    *(float4*)&x[(size_t)n * H + c0] = xv;
  }
}

// ---------------- node-owned MFMA neighbor embedding (no atomics) ----------------
__global__ __launch_bounds__(256) void k_nbr_own(
    const int* __restrict__ starts, const int* __restrict__ counts,
    const int* __restrict__ srcS, const int* __restrict__ dstS,
    const float* __restrict__ CS, const u16* __restrict__ attrG,
    const u16* __restrict__ npWt, const float* __restrict__ npb,
    const float* __restrict__ xn, float* __restrict__ agg)
{
  __shared__ __align__(16) u16 s_red[128 * 136];
  __shared__ int s_src[128], s_dst[128];
  __shared__ float s_C[128];
  int tid = threadIdx.x;
  int lane = tid & 63, wv = tid >> 6;
  int r16 = lane & 15, g4 = lane >> 4;
  int n0 = blockIdx.x * NPB;
  int eStart = starts[n0];
  int eEnd = starts[n0 + NPB];
  float bb[8];
  #pragma unroll
  for (int ct = 0; ct < 8; ++ct) bb[ct] = npb[ct*16 + r16];
  int curDst = -1;
  float accv = 0.f;
  for (int chunk = eStart; chunk < eEnd; chunk += 128) {
    int nv = min(128, eEnd - chunk);
    __syncthreads();
    if (tid < 128) {
      long idx = min((long)(chunk + tid), (long)NE - 1);
      s_src[tid] = srcS[idx];
      s_dst[tid] = dstS[idx];
      s_C[tid]   = CS[idx];
    }
    __syncthreads();
    f32x4 acc[2][8];
    #pragma unroll
    for (int rl = 0; rl < 2; ++rl)
      for (int ct = 0; ct < 8; ++ct) acc[rl][ct] = (f32x4){0.f,0.f,0.f,0.f};
    #pragma unroll
    for (int kt = 0; kt < 2; ++kt) {
      short8v aF[2];
      #pragma unroll
      for (int rl = 0; rl < 2; ++rl) {
        long row = min((long)(chunk + (wv*2+rl)*16 + r16), (long)NE - 1);
        aF[rl] = *(const short8v*)&attrG[row * 64 + kt*32 + g4*8];
      }
      #pragma unroll
      for (int ct = 0; ct < 8; ++ct) {
        short8v bF = *(const short8v*)&npWt[(ct*16 + r16) * 64 + kt*32 + g4*8];
        #pragma unroll
        for (int rl = 0; rl < 2; ++rl)
          acc[rl][ct] = __builtin_amdgcn_mfma_f32_16x16x32_bf16(aF[rl], bF, acc[rl][ct], 0, 0, 0);
      }
    }
    // per-edge products -> bf16 LDS (band-local rows)
    #pragma unroll
    for (int rl = 0; rl < 2; ++rl) {
      #pragma unroll
      for (int r = 0; r < 4; ++r) {
        int e = (wv*2+rl)*16 + g4*4 + r;
        float m = (s_src[e] != s_dst[e]) ? s_C[e] : 0.f;
        const float* hp = xn + (size_t)s_src[e] * H + r16;
        #pragma unroll
        for (int ct = 0; ct < 8; ++ct)
          s_red[e * 136 + ct*16 + r16] = f2b((acc[rl][ct][r] + bb[ct]) * m * hp[ct*16]);
      }
    }
    __syncthreads();
    if (tid < 128) {
      for (int e = 0; e < nv; ++e) {
        float v = b2f(s_red[e * 136 + tid]);
        int dn = s_dst[e];
        if (dn != curDst) {
          if (curDst >= 0) agg[(size_t)curDst * H + tid] = accv;
          accv = 0.f; curDst = dn;
        }
        accv += v;
      }
    }
  }
  if (tid < 128) {
    if (curDst >= 0) agg[(size_t)curDst * H + tid] = accv;
    for (int n = n0; n < n0 + NPB; ++n)
      if (counts[n] == 0) agg[(size_t)n * H + tid] = 0.f;
  }
}

// ---------------- node-owned MFMA CFConv (no atomics) ----------------
__global__ __launch_bounds__(256) void k_cf_own(
    const int* __restrict__ starts, const int* __restrict__ counts,
    const int* __restrict__ srcS, const int* __restrict__ dstS,
    const float* __restrict__ CS, const u16* __restrict__ attrG,
    const u16* __restrict__ w1t, const float* __restrict__ b1,
    const u16* __restrict__ w2t, const float* __restrict__ b2,
    const float* __restrict__ h, float* __restrict__ agg)
{
  __shared__ __align__(16) u16 s_t1[128 * 136];   // t1, then reused as product buf
  __shared__ int s_src[128], s_dst[128];
  __shared__ float s_C[128];
  int tid = threadIdx.x;
  int lane = tid & 63, wv = tid >> 6;
  int r16 = lane & 15, g4 = lane >> 4;
  int n0 = blockIdx.x * NPB;
  int eStart = starts[n0];
  int eEnd = starts[n0 + NPB];
  float bb2[8];
  #pragma unroll
  for (int ct = 0; ct < 8; ++ct) bb2[ct] = b2[ct*16 + r16];
  int curDst = -1;
  float accv = 0.f;
  for (int chunk = eStart; chunk < eEnd; chunk += 128) {
    int nv = min(128, eEnd - chunk);
    __syncthreads();
    if (tid < 128) {
      long idx = min((long)(chunk + tid), (long)NE - 1);
      s_src[tid] = srcS[idx];
      s_dst[tid] = dstS[idx];
      s_C[tid]   = CS[idx];
    }
    __syncthreads();
    // GEMM1: attr @ W1t
    f32x4 acc1[2][8];
    #pragma unroll
    for (int rl = 0; rl < 2; ++rl)
      for (int ct = 0; ct < 8; ++ct) acc1[rl][ct] = (f32x4){0.f,0.f,0.f,0.f};
    #pragma unroll
    for (int kt = 0; kt < 2; ++kt) {
      short8v aF[2];
      #pragma unroll
      for (int rl = 0; rl < 2; ++rl) {
        long row = min((long)(chunk + (wv*2+rl)*16 + r16), (long)NE - 1);
        aF[rl] = *(const short8v*)&attrG[row * 64 + kt*32 + g4*8];
      }
      #pragma unroll
      for (int ct = 0; ct < 8; ++ct) {
        short8v bF = *(const short8v*)&w1t[(ct*16 + r16) * 64 + kt*32 + g4*8];
        #pragma unroll
        for (int rl = 0; rl < 2; ++rl)
          acc1[rl][ct] = __builtin_amdgcn_mfma_f32_16x16x32_bf16(aF[rl], bF, acc1[rl][ct], 0, 0, 0);
      }
    }
    // bias + silu -> bf16 t1 (band-local rows)
    #pragma unroll
    for (int ct = 0; ct < 8; ++ct) {
      int c = ct*16 + r16;
      float bbv = b1[c];
      #pragma unroll
      for (int rl = 0; rl < 2; ++rl) {
        int rbase = (wv*2+rl)*16 + g4*4;
        #pragma unroll
        for (int r = 0; r < 4; ++r) {
          float v = acc1[rl][ct][r] + bbv;
          v = v / (1.f + __expf(-v));
          s_t1[(rbase + r) * 136 + c] = f2b(v);
        }
      }
    }
    // GEMM2: t1 @ W2t (A from own band, B from global)
    f32x4 acc2[2][8];
    #pragma unroll
    for (int rl = 0; rl < 2; ++rl)
      for (int ct = 0; ct < 8; ++ct) acc2[rl][ct] = (f32x4){0.f,0.f,0.f,0.f};
    #pragma unroll
    for (int kt = 0; kt < 4; ++kt) {
      short8v aF[2];
      #pragma unroll
      for (int rl = 0; rl < 2; ++rl)
        aF[rl] = *(const short8v*)&s_t1[((wv*2+rl)*16 + r16) * 136 + kt*32 + g4*8];
      #pragma unroll
      for (int ct = 0; ct < 8; ++ct) {
        short8v bF = *(const short8v*)&w2t[(ct*16 + r16) * 136 + kt*32 + g4*8];
        #pragma unroll
        for (int rl = 0; rl < 2; ++rl)
          acc2[rl][ct] = __builtin_amdgcn_mfma_f32_16x16x32_bf16(aF[rl], bF, acc2[rl][ct], 0, 0, 0);
      }
    }
    // per-edge products (Wf*C*h) -> bf16 LDS (overwrites own band rows of t1)
    #pragma unroll
    for (int rl = 0; rl < 2; ++rl) {
      #pragma unroll
      for (int r = 0; r < 4; ++r) {
        int e = (wv*2+rl)*16 + g4*4 + r;
        float Ce = s_C[e];
        const float* hp = h + (size_t)s_src[e] * H + r16;
        #pragma unroll
        for (int ct = 0; ct < 8; ++ct)
          s_t1[e * 136 + ct*16 + r16] = f2b((acc2[rl][ct][r] + bb2[ct]) * Ce * hp[ct*16]);
      }
    }
    __syncthreads();
    // segmented scan by column (block owns all dsts in range -> plain stores)
    if (tid < 128) {
      for (int e = 0; e < nv; ++e) {
        float v = b2f(s_t1[e * 136 + tid]);
        int dn = s_dst[e];
        if (dn != curDst) {
          if (curDst >= 0) agg[(size_t)curDst * H + tid] = accv;
          accv = 0.f; curDst = dn;
        }
        accv += v;
      }
    }
  }
  if (tid < 128) {
    if (curDst >= 0) agg[(size_t)curDst * H + tid] = accv;
    for (int n = n0; n < n0 + NPB; ++n)
      if (counts[n] == 0) agg[(size_t)n * H + tid] = 0.f;
  }
}

// ---------------- launcher ----------------
extern "C" void kernel_launch(void* const* d_in, const int* in_sizes, int n_in,
                              void* d_out, int out_size, void* d_ws, size_t ws_size,
                              hipStream_t stream) {
  int bo = (n_in >= 4 && in_sizes[3] == NN) ? 0 : -1;  // batch present?
  const int*   z     = (const int*)d_in[0];
  const float* pos   = (const float*)d_in[1];
  const int*   ei    = (const int*)d_in[2];
  const float* emb   = (const float*)d_in[4 + bo];
  const float* nemb  = (const float*)d_in[5 + bo];
  const float* npW   = (const float*)d_in[6 + bo];
  const float* npb   = (const float*)d_in[7 + bo];
  const float* cW    = (const float*)d_in[8 + bo];
  const float* cb    = (const float*)d_in[9 + bo];
  const float* means = (const float*)d_in[10 + bo];
  const float* betas = (const float*)d_in[11 + bo];
  const float* W1    = (const float*)d_in[12 + bo];
  const float* b1    = (const float*)d_in[13 + bo];
  const float* W2    = (const float*)d_in[14 + bo];
  const float* b2    = (const float*)d_in[15 + bo];
  const float* l1W   = (const float*)d_in[16 + bo];
  const float* l2W   = (const float*)d_in[17 + bo];
  const float* l2b   = (const float*)d_in[18 + bo];
  const float* lW    = (const float*)d_in[19 + bo];
  const float* lb    = (const float*)d_in[20 + bo];

  char* w = (char*)d_ws;
  auto alloc = [&](size_t bytes) { char* p = w; w += (bytes + 255) & ~(size_t)255; return p; };
  int*   counts = (int*)  alloc((size_t)NN * 4);
  int*   starts = (int*)  alloc((size_t)(NN + 1) * 4);
  int*   cursor = (int*)  alloc((size_t)NN * 4);
  int*   perm   = (int*)  alloc((size_t)NE * 4);
  int*   srcS   = (int*)  alloc((size_t)NE * 4);
  int*   dstS   = (int*)  alloc((size_t)NE * 4);
  float* CS     = (float*)alloc((size_t)NE * 4);
  u16*   attrG  = (u16*)  alloc((size_t)NE * 64 * 2);
  u16*   npWt   = (u16*)  alloc((size_t)128 * 64 * 2);
  u16*   w1tA   = (u16*)  alloc((size_t)NL * 128 * 64 * 2);
  u16*   w2tA   = (u16*)  alloc((size_t)NL * 128 * 136 * 2);
  float* xbuf   = (float*)alloc((size_t)NN * H * 4);
  float* bufA   = (float*)alloc((size_t)NN * H * 4);
  float* agg    = (float*)alloc((size_t)NN * H * 4);

  dim3 b256(256);
  int gE256 = (NE + 255) / 256;        // 2500
  int gNH   = (NN * H + 255) / 256;    // 10000
  int gOwn  = NN / NPB;                // 5000
  int gG    = NN / 32;                 // 625

  k_zero_i32<<<(NN + 255) / 256, b256, 0, stream>>>(counts, NN);
  k_hist<<<gE256, b256, 0, stream>>>(ei, counts);
  k_scan<<<1, 1024, 0, stream>>>(counts, starts, cursor);
  k_place<<<gE256, b256, 0, stream>>>(ei, cursor, perm);
  k_edge<<<gE256, b256, 0, stream>>>(ei, perm, pos, means, betas, srcS, dstS, CS, attrG);
  k_prepw<<<(161792 + 255) / 256, b256, 0, stream>>>(npW, W1, W2, npWt, w1tA, w2tA);
  k_embed<<<gNH, b256, 0, stream>>>(z, emb, nemb, xbuf, bufA);

  // neighbor embedding (agg fully written by ownership; no zero needed)
  k_nbr_own<<<gOwn, b256, 0, stream>>>(starts, counts, srcS, dstS, CS, attrG,
                                       npWt, npb, bufA, agg);

  // combine: x = [x || agg] @ cW + cb
  k_gemm32<<<gG, b256, 0, stream>>>(xbuf, cW, cb, nullptr, bufA, 0);
  k_gemm32<<<gG, b256, 0, stream>>>(agg, cW + (size_t)128 * H, nullptr, bufA, xbuf, 0);

  for (int l = 0; l < NL; ++l) {
    k_gemm32<<<gG, b256, 0, stream>>>(xbuf, l1W + (size_t)l * H * H, nullptr, nullptr, bufA, 0);
    k_cf_own<<<gOwn, b256, 0, stream>>>(starts, counts, srcS, dstS, CS, attrG,
                                        w1tA + (size_t)l * 128 * 64, b1 + (size_t)l * H,
                                        w2tA + (size_t)l * 128 * 136, b2 + (size_t)l * H,
                                        bufA, agg);
    k_gemmF<<<gG, b256, 0, stream>>>(agg, l2W + (size_t)l * H * H, l2b + (size_t)l * H,
                                     lW + (size_t)l * H * H, lb + (size_t)l * H, xbuf);
  }
  k_out<<<gNH, b256, 0, stream>>>(xbuf, (float*)d_out);
}

// Round 9
// 1714.816 us; speedup vs baseline: 3.1704x; 3.1704x over previous
//
#include <hip/hip_runtime.h>
#include <hip/hip_bf16.h>
#include <math.h>

#define NN 20000
#define NE 640000
#define H  128
#define RB 50
#define NL 6

typedef unsigned short u16;
typedef __attribute__((ext_vector_type(8))) short short8v;
typedef __attribute__((ext_vector_type(4))) float f32x4;

__device__ __forceinline__ u16 f2b(float v) {
  unsigned x = __float_as_uint(v);
  unsigned r = (x + 0x7FFFu + ((x >> 16) & 1u)) >> 16;
  return (u16)r;
}
__device__ __forceinline__ float b2f(u16 u) {
  return __uint_as_float(((unsigned int)u) << 16);
}

// ---------------- sort machinery ----------------
__global__ void k_zero_i32(int* __restrict__ p, int n) {
  int i = blockIdx.x * blockDim.x + threadIdx.x;
  if (i < n) p[i] = 0;
}
__global__ void k_zero_f32(float* __restrict__ p, int n) {
  int i = blockIdx.x * blockDim.x + threadIdx.x;
  if (i < n) p[i] = 0.f;
}
__global__ void k_hist(const int* __restrict__ ei, int* __restrict__ counts) {
  int e = blockIdx.x * blockDim.x + threadIdx.x;
  if (e < NE) atomicAdd(&counts[ei[NE + e]], 1);
}
__global__ void k_scan(const int* __restrict__ counts, int* __restrict__ cursor) {
  __shared__ int buf[1024];
  __shared__ int carry;
  int tid = threadIdx.x;
  if (tid == 0) carry = 0;
  __syncthreads();
  for (int base = 0; base < NN; base += 1024) {
    int i = base + tid;
    int v = (i < NN) ? counts[i] : 0;
    buf[tid] = v;
    __syncthreads();
    for (int off = 1; off < 1024; off <<= 1) {
      int t = (tid >= off) ? buf[tid - off] : 0;
      __syncthreads();
      buf[tid] += t;
      __syncthreads();
    }
    int incl = buf[tid];
    int excl = incl - v + carry;
    if (i < NN) cursor[i] = excl;
    __syncthreads();
    if (tid == 1023) carry += incl;
    __syncthreads();
  }
}
__global__ void k_place(const int* __restrict__ ei, int* __restrict__ cursor,
                        int* __restrict__ perm) {
  int e = blockIdx.x * blockDim.x + threadIdx.x;
  if (e < NE) {
    int d = ei[NE + e];
    int p = atomicAdd(&cursor[d], 1);
    perm[p] = e;
  }
}

// ---------------- edge precompute ----------------
__global__ void k_edge(const int* __restrict__ ei, const int* __restrict__ perm,
                       const float* __restrict__ pos, const float* __restrict__ means,
                       const float* __restrict__ betas,
                       int* __restrict__ srcS, int* __restrict__ dstS,
                       float* __restrict__ CS, u16* __restrict__ attrG) {
  int p = blockIdx.x * 256 + threadIdx.x;
  if (p >= NE) return;
  int e = perm[p];
  int s = ei[e], t = ei[NE + e];
  srcS[p] = s; dstS[p] = t;
  float dx = pos[3*s]   - pos[3*t];
  float dy = pos[3*s+1] - pos[3*t+1];
  float dz = pos[3*s+2] - pos[3*t+2];
  float d = sqrtf(dx*dx + dy*dy + dz*dz);
  float C = 0.5f * (cosf(d * 0.628318530717958647692f) + 1.0f);
  if (d >= 5.0f) C = 0.f;
  CS[p] = C;
  float tv = expf(-d);
  u16* row = attrG + (size_t)p * 64;
  for (int k = 0; k < RB; ++k) {
    float diff = tv - means[k];
    row[k] = f2b(C * expf(-betas[k] * diff * diff));
  }
  for (int k = RB; k < 64; ++k) row[k] = 0;
}

// ---------------- weight pre-transpose/convert to bf16 ----------------
__global__ void k_prepw(const float* __restrict__ npW, const float* __restrict__ W1,
                        const float* __restrict__ W2, u16* __restrict__ npWt,
                        u16* __restrict__ w1tA, u16* __restrict__ w2tA) {
  int i = blockIdx.x * 256 + threadIdx.x;
  if (i < 8192) {
    int n = i >> 6, k = i & 63;
    npWt[i] = (k < RB) ? f2b(npW[k * H + n]) : (u16)0;
  } else if (i < 57344) {
    int j = i - 8192;
    int l = j >> 13, r = j & 8191;
    int n = r >> 6, k = r & 63;
    w1tA[j] = (k < RB) ? f2b(W1[(size_t)l * RB * H + (size_t)k * H + n]) : (u16)0;
  } else if (i < 161792) {
    int j = i - 57344;
    int l = j / 17408, r = j % 17408;
    int n = r / 136, k = r % 136;
    w2tA[j] = (k < H) ? f2b(W2[(size_t)l * H * H + (size_t)k * H + n]) : (u16)0;
  }
}

// x f32; xn bf16 (for latency-hidden gathers)
__global__ void k_embed(const int* __restrict__ z, const float* __restrict__ emb,
                        const float* __restrict__ nemb,
                        float* __restrict__ x, u16* __restrict__ xnb) {
  int i = blockIdx.x * blockDim.x + threadIdx.x;
  if (i >= NN * H) return;
  int n = i >> 7, c = i & (H - 1);
  long o = (long)z[n] * H + c;
  x[i]   = emb[o];
  xnb[i] = f2b(nemb[o]);
}

__global__ void k_out(const float* __restrict__ x, float* __restrict__ out) {
  int i = blockIdx.x * blockDim.x + threadIdx.x;
  if (i < NN * H) out[i] = x[i];
}

// ---------------- node GEMM, M-tile 32, optional bf16 out ----------------
__global__ __launch_bounds__(256) void k_gemm32(
    const float* __restrict__ A, const float* __restrict__ W,
    const float* __restrict__ bias, const float* __restrict__ add,
    void* __restrict__ out, int useAct, int obf)
{
  __shared__ float sA[32][132];
  int tid = threadIdx.x;
  int n0 = blockIdx.x * 32;
  #pragma unroll
  for (int j = 0; j < 4; ++j) {
    int f4 = tid + j * 256;
    int r = f4 >> 5, c4 = f4 & 31;
    *(float4*)&sA[r][c4 * 4] = *(const float4*)&A[(size_t)(n0 + r) * H + c4 * 4];
  }
  __syncthreads();
  int g = tid >> 5;
  int c0 = (tid & 31) * 4;
  int eb = g * 4;
  float acc[4][4];
  #pragma unroll
  for (int i = 0; i < 4; ++i)
    for (int j = 0; j < 4; ++j) acc[i][j] = 0.f;
  for (int k = 0; k < H; ++k) {
    float4 wv = *(const float4*)&W[(size_t)k * H + c0];
    #pragma unroll
    for (int i = 0; i < 4; ++i) {
      float a = sA[eb + i][k];
      acc[i][0] += a * wv.x; acc[i][1] += a * wv.y;
      acc[i][2] += a * wv.z; acc[i][3] += a * wv.w;
    }
  }
  float bv[4] = {0.f, 0.f, 0.f, 0.f};
  if (bias) {
    float4 b4 = *(const float4*)&bias[c0];
    bv[0] = b4.x; bv[1] = b4.y; bv[2] = b4.z; bv[3] = b4.w;
  }
  #pragma unroll
  for (int i = 0; i < 4; ++i) {
    int n = n0 + eb + i;
    float o[4];
    #pragma unroll
    for (int j = 0; j < 4; ++j) {
      float v = acc[i][j] + bv[j];
      if (useAct) v = v / (1.f + __expf(-v));
      o[j] = v;
    }
    if (add) {
      float4 a4 = *(const float4*)&add[(size_t)n * H + c0];
      o[0] += a4.x; o[1] += a4.y; o[2] += a4.z; o[3] += a4.w;
    }
    if (obf) {
      ushort4 ov;
      ov.x = f2b(o[0]); ov.y = f2b(o[1]); ov.z = f2b(o[2]); ov.w = f2b(o[3]);
      *(ushort4*)&((u16*)out)[(size_t)n * H + c0] = ov;
    } else {
      *(float4*)&((float*)out)[(size_t)n * H + c0] = make_float4(o[0], o[1], o[2], o[3]);
    }
  }
}

// ---------------- fused lin2+lin: x = x + (silu(A@W2+b2))@W3 + b3 ----------------
__global__ __launch_bounds__(256) void k_gemmF(
    const float* __restrict__ A, const float* __restrict__ W2,
    const float* __restrict__ b2, const float* __restrict__ W3,
    const float* __restrict__ b3, float* __restrict__ x)
{
  __shared__ float sA[32][132];
  __shared__ float sT[32][132];
  int tid = threadIdx.x;
  int n0 = blockIdx.x * 32;
  #pragma unroll
  for (int j = 0; j < 4; ++j) {
    int f4 = tid + j * 256;
    int r = f4 >> 5, c4 = f4 & 31;
    *(float4*)&sA[r][c4 * 4] = *(const float4*)&A[(size_t)(n0 + r) * H + c4 * 4];
  }
  __syncthreads();
  int g = tid >> 5;
  int c0 = (tid & 31) * 4;
  int eb = g * 4;
  float acc[4][4];
  #pragma unroll
  for (int i = 0; i < 4; ++i)
    for (int j = 0; j < 4; ++j) acc[i][j] = 0.f;
  for (int k = 0; k < H; ++k) {
    float4 wv = *(const float4*)&W2[(size_t)k * H + c0];
    #pragma unroll
    for (int i = 0; i < 4; ++i) {
      float a = sA[eb + i][k];
      acc[i][0] += a * wv.x; acc[i][1] += a * wv.y;
      acc[i][2] += a * wv.z; acc[i][3] += a * wv.w;
    }
  }
  float4 bv2 = *(const float4*)&b2[c0];
  #pragma unroll
  for (int i = 0; i < 4; ++i) {
    float t0 = acc[i][0] + bv2.x, t1 = acc[i][1] + bv2.y;
    float t2 = acc[i][2] + bv2.z, t3 = acc[i][3] + bv2.w;
    sT[eb + i][c0 + 0] = t0 / (1.f + __expf(-t0));
    sT[eb + i][c0 + 1] = t1 / (1.f + __expf(-t1));
    sT[eb + i][c0 + 2] = t2 / (1.f + __expf(-t2));
    sT[eb + i][c0 + 3] = t3 / (1.f + __expf(-t3));
  }
  __syncthreads();
  #pragma unroll
  for (int i = 0; i < 4; ++i)
    for (int j = 0; j < 4; ++j) acc[i][j] = 0.f;
  for (int k = 0; k < H; ++k) {
    float4 wv = *(const float4*)&W3[(size_t)k * H + c0];
    #pragma unroll
    for (int i = 0; i < 4; ++i) {
      float a = sT[eb + i][k];
      acc[i][0] += a * wv.x; acc[i][1] += a * wv.y;
      acc[i][2] += a * wv.z; acc[i][3] += a * wv.w;
    }
  }
  float4 bv3 = *(const float4*)&b3[c0];
  #pragma unroll
  for (int i = 0; i < 4; ++i) {
    int n = n0 + eb + i;
    float4 xv = *(const float4*)&x[(size_t)n * H + c0];
    xv.x += acc[i][0] + bv3.x; xv.y += acc[i][1] + bv3.y;
    xv.z += acc[i][2] + bv3.z; xv.w += acc[i][3] + bv3.w;
    *(float4*)&x[(size_t)n * H + c0] = xv;
  }
}

// ---------------- MFMA neighbor embedding with prefetch + band-merge ----------------
__global__ __launch_bounds__(256) void k_nbr_pre(
    const int* __restrict__ srcS, const int* __restrict__ dstS,
    const float* __restrict__ CS, const u16* __restrict__ attrG,
    const u16* __restrict__ npWt, const float* __restrict__ npb,
    const u16* __restrict__ xnb, float* __restrict__ agg)
{
  __shared__ __align__(16) u16 s_h[128 * 136];
  __shared__ int s_src[128], s_dst[128];
  __shared__ float s_C[128];
  int tid = threadIdx.x;
  int lane = tid & 63, wv = tid >> 6;
  int r16 = lane & 15, g4 = lane >> 4;
  long base = (long)blockIdx.x * 128;
  if (tid < 128) {
    s_src[tid] = srcS[base + tid];
    s_dst[tid] = dstS[base + tid];
    s_C[tid]   = CS[base + tid];
  }
  __syncthreads();
  // prefetch: lane covers 64B of one xn row; 4 lanes/edge; both bands upfront
  short8v hpA[4], hpB[4];
  {
    int elA = wv * 32 + (lane >> 2);
    int elB = elA + 16;
    const u16* hpa = xnb + (size_t)s_src[elA] * H + (lane & 3) * 32;
    const u16* hpb = xnb + (size_t)s_src[elB] * H + (lane & 3) * 32;
    #pragma unroll
    for (int j = 0; j < 4; ++j) { hpA[j] = *(const short8v*)(hpa + 8*j); hpB[j] = *(const short8v*)(hpb + 8*j); }
  }
  // GEMM1: attr @ npWt
  f32x4 acc[2][8];
  #pragma unroll
  for (int rl = 0; rl < 2; ++rl)
    for (int ct = 0; ct < 8; ++ct) acc[rl][ct] = (f32x4){0.f,0.f,0.f,0.f};
  #pragma unroll
  for (int kt = 0; kt < 2; ++kt) {
    short8v aF[2];
    #pragma unroll
    for (int rl = 0; rl < 2; ++rl)
      aF[rl] = *(const short8v*)&attrG[(base + (wv*2+rl)*16 + r16) * 64 + kt*32 + g4*8];
    #pragma unroll
    for (int ct = 0; ct < 8; ++ct) {
      short8v bF = *(const short8v*)&npWt[(ct*16 + r16) * 64 + kt*32 + g4*8];
      #pragma unroll
      for (int rl = 0; rl < 2; ++rl)
        acc[rl][ct] = __builtin_amdgcn_mfma_f32_16x16x32_bf16(aF[rl], bF, acc[rl][ct], 0, 0, 0);
    }
  }
  // stage prefetched xn rows into own band region
  {
    int elA = wv * 32 + (lane >> 2);
    u16* d0 = &s_h[(size_t)elA * 136 + (lane & 3) * 32];
    u16* d1 = &s_h[(size_t)(elA + 16) * 136 + (lane & 3) * 32];
    #pragma unroll
    for (int j = 0; j < 4; ++j) { *(short8v*)(d0 + 8*j) = hpA[j]; *(short8v*)(d1 + 8*j) = hpB[j]; }
  }
  __syncthreads();
  // epilogue
  float bb[8];
  #pragma unroll
  for (int ct = 0; ct < 8; ++ct) bb[ct] = npb[ct*16 + r16];
  float vsum[8];
  int pdst = -1;
  #pragma unroll
  for (int rl = 0; rl < 2; ++rl) {
    int brow = wv*32 + rl*16;
    int d0 = s_dst[brow], d15 = s_dst[brow + 15];
    if (d0 == d15) {
      float part[8];
      #pragma unroll
      for (int ct = 0; ct < 8; ++ct) part[ct] = 0.f;
      #pragma unroll
      for (int r = 0; r < 4; ++r) {
        int e = brow + g4*4 + r;
        float m = (s_src[e] != d0) ? s_C[e] : 0.f;
        #pragma unroll
        for (int ct = 0; ct < 8; ++ct)
          part[ct] += (acc[rl][ct][r] + bb[ct]) * m * b2f(s_h[e * 136 + ct*16 + r16]);
      }
      #pragma unroll
      for (int ct = 0; ct < 8; ++ct) {
        part[ct] += __shfl_xor(part[ct], 16, 64);
        part[ct] += __shfl_xor(part[ct], 32, 64);
      }
      if (g4 == 0) {
        if (d0 != pdst) {
          if (pdst >= 0) {
            float* ap = agg + (size_t)pdst * H + r16;
            #pragma unroll
            for (int ct = 0; ct < 8; ++ct) atomicAdd(ap + ct*16, vsum[ct]);
          }
          #pragma unroll
          for (int ct = 0; ct < 8; ++ct) vsum[ct] = 0.f;
          pdst = d0;
        }
        #pragma unroll
        for (int ct = 0; ct < 8; ++ct) vsum[ct] += part[ct];
      }
    } else {
      #pragma unroll
      for (int r = 0; r < 4; ++r) {
        int e = brow + g4*4 + r;
        int dn = s_dst[e];
        float m = (s_src[e] != dn) ? s_C[e] : 0.f;
        if (dn != pdst) {
          if (pdst >= 0) {
            float* ap = agg + (size_t)pdst * H + r16;
            #pragma unroll
            for (int ct = 0; ct < 8; ++ct) atomicAdd(ap + ct*16, vsum[ct]);
          }
          #pragma unroll
          for (int ct = 0; ct < 8; ++ct) vsum[ct] = 0.f;
          pdst = dn;
        }
        #pragma unroll
        for (int ct = 0; ct < 8; ++ct)
          vsum[ct] += (acc[rl][ct][r] + bb[ct]) * m * b2f(s_h[e * 136 + ct*16 + r16]);
      }
    }
  }
  if (pdst >= 0) {
    float* ap = agg + (size_t)pdst * H + r16;
    #pragma unroll
    for (int ct = 0; ct < 8; ++ct) atomicAdd(ap + ct*16, vsum[ct]);
  }
}

// ---------------- MFMA CFConv with prefetch + band-merge ----------------
__global__ __launch_bounds__(256) void k_cf_pre(
    const int* __restrict__ srcS, const int* __restrict__ dstS,
    const float* __restrict__ CS, const u16* __restrict__ attrG,
    const u16* __restrict__ w1t, const float* __restrict__ b1,
    const u16* __restrict__ w2t, const float* __restrict__ b2,
    const u16* __restrict__ h, float* __restrict__ agg)
{
  __shared__ __align__(16) u16 s_t1[128 * 136];   // t1; own band reused as h stage
  __shared__ int s_src[128], s_dst[128];
  __shared__ float s_C[128];
  int tid = threadIdx.x;
  int lane = tid & 63, wv = tid >> 6;
  int r16 = lane & 15, g4 = lane >> 4;
  long base = (long)blockIdx.x * 128;
  if (tid < 128) {
    s_src[tid] = srcS[base + tid];
    s_dst[tid] = dstS[base + tid];
    s_C[tid]   = CS[base + tid];
  }
  __syncthreads();
  // prefetch phase A (band rl=0)
  short8v hpA[4];
  {
    int elA = wv * 32 + (lane >> 2);
    const u16* hpa = h + (size_t)s_src[elA] * H + (lane & 3) * 32;
    #pragma unroll
    for (int j = 0; j < 4; ++j) hpA[j] = *(const short8v*)(hpa + 8*j);
  }
  // GEMM1: attr @ W1t
  f32x4 acc1[2][8];
  #pragma unroll
  for (int rl = 0; rl < 2; ++rl)
    for (int ct = 0; ct < 8; ++ct) acc1[rl][ct] = (f32x4){0.f,0.f,0.f,0.f};
  #pragma unroll
  for (int kt = 0; kt < 2; ++kt) {
    short8v aF[2];
    #pragma unroll
    for (int rl = 0; rl < 2; ++rl)
      aF[rl] = *(const short8v*)&attrG[(base + (wv*2+rl)*16 + r16) * 64 + kt*32 + g4*8];
    #pragma unroll
    for (int ct = 0; ct < 8; ++ct) {
      short8v bF = *(const short8v*)&w1t[(ct*16 + r16) * 64 + kt*32 + g4*8];
      #pragma unroll
      for (int rl = 0; rl < 2; ++rl)
        acc1[rl][ct] = __builtin_amdgcn_mfma_f32_16x16x32_bf16(aF[rl], bF, acc1[rl][ct], 0, 0, 0);
    }
  }
  // prefetch phase B (band rl=1) — overlaps silu + GEMM2
  short8v hpB[4];
  {
    int elB = wv * 32 + 16 + (lane >> 2);
    const u16* hpb = h + (size_t)s_src[elB] * H + (lane & 3) * 32;
    #pragma unroll
    for (int j = 0; j < 4; ++j) hpB[j] = *(const short8v*)(hpb + 8*j);
  }
  // bias + silu -> bf16 t1 (band-local rows)
  #pragma unroll
  for (int ct = 0; ct < 8; ++ct) {
    int c = ct*16 + r16;
    float bbv = b1[c];
    #pragma unroll
    for (int rl = 0; rl < 2; ++rl) {
      int rbase = (wv*2+rl)*16 + g4*4;
      #pragma unroll
      for (int r = 0; r < 4; ++r) {
        float v = acc1[rl][ct][r] + bbv;
        v = v / (1.f + __expf(-v));
        s_t1[(rbase + r) * 136 + c] = f2b(v);
      }
    }
  }
  // GEMM2: t1 @ W2t (A from own band)
  f32x4 acc2[2][8];
  #pragma unroll
  for (int rl = 0; rl < 2; ++rl)
    for (int ct = 0; ct < 8; ++ct) acc2[rl][ct] = (f32x4){0.f,0.f,0.f,0.f};
  #pragma unroll
  for (int kt = 0; kt < 4; ++kt) {
    short8v aF[2];
    #pragma unroll
    for (int rl = 0; rl < 2; ++rl)
      aF[rl] = *(const short8v*)&s_t1[((wv*2+rl)*16 + r16) * 136 + kt*32 + g4*8];
    #pragma unroll
    for (int ct = 0; ct < 8; ++ct) {
      short8v bF = *(const short8v*)&w2t[(ct*16 + r16) * 136 + kt*32 + g4*8];
      #pragma unroll
      for (int rl = 0; rl < 2; ++rl)
        acc2[rl][ct] = __builtin_amdgcn_mfma_f32_16x16x32_bf16(aF[rl], bF, acc2[rl][ct], 0, 0, 0);
    }
  }
  // stage prefetched h rows into own (now dead) t1 band
  {
    int elA = wv * 32 + (lane >> 2);
    u16* d0 = &s_t1[(size_t)elA * 136 + (lane & 3) * 32];
    u16* d1 = &s_t1[(size_t)(elA + 16) * 136 + (lane & 3) * 32];
    #pragma unroll
    for (int j = 0; j < 4; ++j) { *(short8v*)(d0 + 8*j) = hpA[j]; *(short8v*)(d1 + 8*j) = hpB[j]; }
  }
  __syncthreads();
  // epilogue: Wf = (acc2+b2)*C; val = Wf * h[src]; band-merged run-merge atomics
  float bb2[8];
  #pragma unroll
  for (int ct = 0; ct < 8; ++ct) bb2[ct] = b2[ct*16 + r16];
  float vsum[8];
  int pdst = -1;
  #pragma unroll
  for (int rl = 0; rl < 2; ++rl) {
    int brow = wv*32 + rl*16;
    int d0 = s_dst[brow], d15 = s_dst[brow + 15];
    if (d0 == d15) {
      float part[8];
      #pragma unroll
      for (int ct = 0; ct < 8; ++ct) part[ct] = 0.f;
      #pragma unroll
      for (int r = 0; r < 4; ++r) {
        int e = brow + g4*4 + r;
        float Ce = s_C[e];
        #pragma unroll
        for (int ct = 0; ct < 8; ++ct)
          part[ct] += (acc2[rl][ct][r] + bb2[ct]) * Ce * b2f(s_t1[e * 136 + ct*16 + r16]);
      }
      #pragma unroll
      for (int ct = 0; ct < 8; ++ct) {
        part[ct] += __shfl_xor(part[ct], 16, 64);
        part[ct] += __shfl_xor(part[ct], 32, 64);
      }
      if (g4 == 0) {
        if (d0 != pdst) {
          if (pdst >= 0) {
            float* ap = agg + (size_t)pdst * H + r16;
            #pragma unroll
            for (int ct = 0; ct < 8; ++ct) atomicAdd(ap + ct*16, vsum[ct]);
          }
          #pragma unroll
          for (int ct = 0; ct < 8; ++ct) vsum[ct] = 0.f;
          pdst = d0;
        }
        #pragma unroll
        for (int ct = 0; ct < 8; ++ct) vsum[ct] += part[ct];
      }
    } else {
      #pragma unroll
      for (int r = 0; r < 4; ++r) {
        int e = brow + g4*4 + r;
        int dn = s_dst[e];
        float Ce = s_C[e];
        if (dn != pdst) {
          if (pdst >= 0) {
            float* ap = agg + (size_t)pdst * H + r16;
            #pragma unroll
            for (int ct = 0; ct < 8; ++ct) atomicAdd(ap + ct*16, vsum[ct]);
          }
          #pragma unroll
          for (int ct = 0; ct < 8; ++ct) vsum[ct] = 0.f;
          pdst = dn;
        }
        #pragma unroll
        for (int ct = 0; ct < 8; ++ct)
          vsum[ct] += (acc2[rl][ct][r] + bb2[ct]) * Ce * b2f(s_t1[e * 136 + ct*16 + r16]);
      }
    }
  }
  if (pdst >= 0) {
    float* ap = agg + (size_t)pdst * H + r16;
    #pragma unroll
    for (int ct = 0; ct < 8; ++ct) atomicAdd(ap + ct*16, vsum[ct]);
  }
}

// ---------------- launcher ----------------
extern "C" void kernel_launch(void* const* d_in, const int* in_sizes, int n_in,
                              void* d_out, int out_size, void* d_ws, size_t ws_size,
                              hipStream_t stream) {
  int bo = (n_in >= 4 && in_sizes[3] == NN) ? 0 : -1;  // batch present?
  const int*   z     = (const int*)d_in[0];
  const float* pos   = (const float*)d_in[1];
  const int*   ei    = (const int*)d_in[2];
  const float* emb   = (const float*)d_in[4 + bo];
  const float* nemb  = (const float*)d_in[5 + bo];
  const float* npW   = (const float*)d_in[6 + bo];
  const float* npb   = (const float*)d_in[7 + bo];
  const float* cW    = (const float*)d_in[8 + bo];
  const float* cb    = (const float*)d_in[9 + bo];
  const float* means = (const float*)d_in[10 + bo];
  const float* betas = (const float*)d_in[11 + bo];
  const float* W1    = (const float*)d_in[12 + bo];
  const float* b1    = (const float*)d_in[13 + bo];
  const float* W2    = (const float*)d_in[14 + bo];
  const float* b2    = (const float*)d_in[15 + bo];
  const float* l1W   = (const float*)d_in[16 + bo];
  const float* l2W   = (const float*)d_in[17 + bo];
  const float* l2b   = (const float*)d_in[18 + bo];
  const float* lW    = (const float*)d_in[19 + bo];
  const float* lb    = (const float*)d_in[20 + bo];

  char* w = (char*)d_ws;
  auto alloc = [&](size_t bytes) { char* p = w; w += (bytes + 255) & ~(size_t)255; return p; };
  int*   counts = (int*)  alloc((size_t)NN * 4);
  int*   cursor = (int*)  alloc((size_t)NN * 4);
  int*   perm   = (int*)  alloc((size_t)NE * 4);
  int*   srcS   = (int*)  alloc((size_t)NE * 4);
  int*   dstS   = (int*)  alloc((size_t)NE * 4);
  float* CS     = (float*)alloc((size_t)NE * 4);
  u16*   attrG  = (u16*)  alloc((size_t)NE * 64 * 2);
  u16*   npWt   = (u16*)  alloc((size_t)128 * 64 * 2);
  u16*   w1tA   = (u16*)  alloc((size_t)NL * 128 * 64 * 2);
  u16*   w2tA   = (u16*)  alloc((size_t)NL * 128 * 136 * 2);
  float* xbuf   = (float*)alloc((size_t)NN * H * 4);
  float* bufA   = (float*)alloc((size_t)NN * H * 4);
  float* agg    = (float*)alloc((size_t)NN * H * 4);
  u16*   xnb    = (u16*)  alloc((size_t)NN * H * 2);
  u16*   hbuf   = (u16*)  alloc((size_t)NN * H * 2);

  dim3 b256(256);
  int gE256 = (NE + 255) / 256;        // 2500
  int gNH   = (NN * H + 255) / 256;    // 10000
  int gCF   = NE / 128;                // 5000
  int gG    = NN / 32;                 // 625

  k_zero_i32<<<(NN + 255) / 256, b256, 0, stream>>>(counts, NN);
  k_hist<<<gE256, b256, 0, stream>>>(ei, counts);
  k_scan<<<1, 1024, 0, stream>>>(counts, cursor);
  k_place<<<gE256, b256, 0, stream>>>(ei, cursor, perm);
  k_edge<<<gE256, b256, 0, stream>>>(ei, perm, pos, means, betas, srcS, dstS, CS, attrG);
  k_prepw<<<(161792 + 255) / 256, b256, 0, stream>>>(npW, W1, W2, npWt, w1tA, w2tA);
  k_embed<<<gNH, b256, 0, stream>>>(z, emb, nemb, xbuf, xnb);

  // neighbor embedding
  k_zero_f32<<<gNH, b256, 0, stream>>>(agg, NN * H);
  k_nbr_pre<<<gCF, b256, 0, stream>>>(srcS, dstS, CS, attrG, npWt, npb, xnb, agg);

  // combine: x = [x || agg] @ cW + cb
  k_gemm32<<<gG, b256, 0, stream>>>(xbuf, cW, cb, nullptr, bufA, 0, 0);
  k_gemm32<<<gG, b256, 0, stream>>>(agg, cW + (size_t)128 * H, nullptr, bufA, xbuf, 0, 0);

  for (int l = 0; l < NL; ++l) {
    k_gemm32<<<gG, b256, 0, stream>>>(xbuf, l1W + (size_t)l * H * H, nullptr, nullptr, hbuf, 0, 1);
    k_zero_f32<<<gNH, b256, 0, stream>>>(agg, NN * H);
    k_cf_pre<<<gCF, b256, 0, stream>>>(srcS, dstS, CS, attrG,
                                       w1tA + (size_t)l * 128 * 64, b1 + (size_t)l * H,
                                       w2tA + (size_t)l * 128 * 136, b2 + (size_t)l * H,
                                       hbuf, agg);
    k_gemmF<<<gG, b256, 0, stream>>>(agg, l2W + (size_t)l * H * H, l2b + (size_t)l * H,
                                     lW + (size_t)l * H * H, lb + (size_t)l * H, xbuf);
  }
  k_out<<<gNH, b256, 0, stream>>>(xbuf, (float*)d_out);
}

// Round 10
// 1689.240 us; speedup vs baseline: 3.2184x; 1.0151x over previous
//
#include <hip/hip_runtime.h>
#include <hip/hip_bf16.h>
#include <math.h>

#define NN 20000
#define NE 640000
#define H  128
#define RB 50
#define NL 6

typedef unsigned short u16;
typedef __attribute__((ext_vector_type(8))) short short8v;
typedef __attribute__((ext_vector_type(4))) float f32x4;

__device__ __forceinline__ u16 f2b(float v) {
  unsigned x = __float_as_uint(v);
  unsigned r = (x + 0x7FFFu + ((x >> 16) & 1u)) >> 16;
  return (u16)r;
}
__device__ __forceinline__ float b2f(u16 u) {
  return __uint_as_float(((unsigned int)u) << 16);
}

// ---------------- sort machinery ----------------
__global__ void k_zero_i32(int* __restrict__ p, int n) {
  int i = blockIdx.x * blockDim.x + threadIdx.x;
  if (i < n) p[i] = 0;
}
__global__ void k_zero_f32(float* __restrict__ p, int n) {
  int i = blockIdx.x * blockDim.x + threadIdx.x;
  if (i < n) p[i] = 0.f;
}
__global__ void k_hist(const int* __restrict__ ei, int* __restrict__ counts) {
  int e = blockIdx.x * blockDim.x + threadIdx.x;
  if (e < NE) atomicAdd(&counts[ei[NE + e]], 1);
}
__global__ void k_scan(const int* __restrict__ counts, int* __restrict__ cursor) {
  __shared__ int buf[1024];
  __shared__ int carry;
  int tid = threadIdx.x;
  if (tid == 0) carry = 0;
  __syncthreads();
  for (int base = 0; base < NN; base += 1024) {
    int i = base + tid;
    int v = (i < NN) ? counts[i] : 0;
    buf[tid] = v;
    __syncthreads();
    for (int off = 1; off < 1024; off <<= 1) {
      int t = (tid >= off) ? buf[tid - off] : 0;
      __syncthreads();
      buf[tid] += t;
      __syncthreads();
    }
    int incl = buf[tid];
    int excl = incl - v + carry;
    if (i < NN) cursor[i] = excl;
    __syncthreads();
    if (tid == 1023) carry += incl;
    __syncthreads();
  }
}
__global__ void k_place(const int* __restrict__ ei, int* __restrict__ cursor,
                        int* __restrict__ perm) {
  int e = blockIdx.x * blockDim.x + threadIdx.x;
  if (e < NE) {
    int d = ei[NE + e];
    int p = atomicAdd(&cursor[d], 1);
    perm[p] = e;
  }
}

// ---------------- edge precompute ----------------
__global__ void k_edge(const int* __restrict__ ei, const int* __restrict__ perm,
                       const float* __restrict__ pos, const float* __restrict__ means,
                       const float* __restrict__ betas,
                       int* __restrict__ srcS, int* __restrict__ dstS,
                       float* __restrict__ CS, u16* __restrict__ attrG) {
  int p = blockIdx.x * 256 + threadIdx.x;
  if (p >= NE) return;
  int e = perm[p];
  int s = ei[e], t = ei[NE + e];
  srcS[p] = s; dstS[p] = t;
  float dx = pos[3*s]   - pos[3*t];
  float dy = pos[3*s+1] - pos[3*t+1];
  float dz = pos[3*s+2] - pos[3*t+2];
  float d = sqrtf(dx*dx + dy*dy + dz*dz);
  float C = 0.5f * (cosf(d * 0.628318530717958647692f) + 1.0f);
  if (d >= 5.0f) C = 0.f;
  CS[p] = C;
  float tv = expf(-d);
  u16* row = attrG + (size_t)p * 64;
  for (int k = 0; k < RB; ++k) {
    float diff = tv - means[k];
    row[k] = f2b(C * expf(-betas[k] * diff * diff));
  }
  for (int k = RB; k < 64; ++k) row[k] = 0;
}

// ---------------- weight pre-transpose/convert to bf16 ----------------
__global__ void k_prepw(const float* __restrict__ npW, const float* __restrict__ W1,
                        const float* __restrict__ W2, u16* __restrict__ npWt,
                        u16* __restrict__ w1tA, u16* __restrict__ w2tA) {
  int i = blockIdx.x * 256 + threadIdx.x;
  if (i < 8192) {
    int n = i >> 6, k = i & 63;
    npWt[i] = (k < RB) ? f2b(npW[k * H + n]) : (u16)0;
  } else if (i < 57344) {
    int j = i - 8192;
    int l = j >> 13, r = j & 8191;
    int n = r >> 6, k = r & 63;
    w1tA[j] = (k < RB) ? f2b(W1[(size_t)l * RB * H + (size_t)k * H + n]) : (u16)0;
  } else if (i < 161792) {
    int j = i - 57344;
    int l = j / 17408, r = j % 17408;
    int n = r / 136, k = r % 136;
    w2tA[j] = (k < H) ? f2b(W2[(size_t)l * H * H + (size_t)k * H + n]) : (u16)0;
  }
}

__global__ void k_embed(const int* __restrict__ z, const float* __restrict__ emb,
                        const float* __restrict__ nemb,
                        float* __restrict__ x, u16* __restrict__ xnb) {
  int i = blockIdx.x * blockDim.x + threadIdx.x;
  if (i >= NN * H) return;
  int n = i >> 7, c = i & (H - 1);
  long o = (long)z[n] * H + c;
  x[i]   = emb[o];
  xnb[i] = f2b(nemb[o]);
}

// ---------------- combine: x = [x||agg]@cW + cb;  h0 = x@l1W0 (bf16) ----------------
__global__ __launch_bounds__(256) void k_combine(
    const float* __restrict__ xb, const float* __restrict__ ag,
    const float* __restrict__ cW, const float* __restrict__ cb,
    const float* __restrict__ l1W0, float* __restrict__ xout,
    u16* __restrict__ hb)
{
  __shared__ float sX[32][132];
  __shared__ float sG[32][132];
  int tid = threadIdx.x;
  int n0 = blockIdx.x * 32;
  #pragma unroll
  for (int j = 0; j < 4; ++j) {
    int f4 = tid + j * 256;
    int r = f4 >> 5, c4 = f4 & 31;
    *(float4*)&sX[r][c4 * 4] = *(const float4*)&xb[(size_t)(n0 + r) * H + c4 * 4];
    *(float4*)&sG[r][c4 * 4] = *(const float4*)&ag[(size_t)(n0 + r) * H + c4 * 4];
  }
  __syncthreads();
  int g = tid >> 5;
  int c0 = (tid & 31) * 4;
  int eb = g * 4;
  float acc[4][4];
  #pragma unroll
  for (int i = 0; i < 4; ++i)
    for (int j = 0; j < 4; ++j) acc[i][j] = 0.f;
  for (int k = 0; k < H; ++k) {
    float4 wv = *(const float4*)&cW[(size_t)k * H + c0];
    #pragma unroll
    for (int i = 0; i < 4; ++i) {
      float a = sX[eb + i][k];
      acc[i][0] += a * wv.x; acc[i][1] += a * wv.y;
      acc[i][2] += a * wv.z; acc[i][3] += a * wv.w;
    }
  }
  for (int k = 0; k < H; ++k) {
    float4 wv = *(const float4*)&cW[(size_t)(H + k) * H + c0];
    #pragma unroll
    for (int i = 0; i < 4; ++i) {
      float a = sG[eb + i][k];
      acc[i][0] += a * wv.x; acc[i][1] += a * wv.y;
      acc[i][2] += a * wv.z; acc[i][3] += a * wv.w;
    }
  }
  float4 bv = *(const float4*)&cb[c0];
  #pragma unroll
  for (int i = 0; i < 4; ++i) {
    int n = n0 + eb + i;
    float o0 = acc[i][0] + bv.x, o1 = acc[i][1] + bv.y;
    float o2 = acc[i][2] + bv.z, o3 = acc[i][3] + bv.w;
    *(float4*)&xout[(size_t)n * H + c0] = make_float4(o0, o1, o2, o3);
    sX[eb + i][c0] = o0; sX[eb + i][c0+1] = o1;
    sX[eb + i][c0+2] = o2; sX[eb + i][c0+3] = o3;
  }
  __syncthreads();
  #pragma unroll
  for (int i = 0; i < 4; ++i)
    for (int j = 0; j < 4; ++j) acc[i][j] = 0.f;
  for (int k = 0; k < H; ++k) {
    float4 wv = *(const float4*)&l1W0[(size_t)k * H + c0];
    #pragma unroll
    for (int i = 0; i < 4; ++i) {
      float a = sX[eb + i][k];
      acc[i][0] += a * wv.x; acc[i][1] += a * wv.y;
      acc[i][2] += a * wv.z; acc[i][3] += a * wv.w;
    }
  }
  #pragma unroll
  for (int i = 0; i < 4; ++i) {
    int n = n0 + eb + i;
    ushort4 ov;
    ov.x = f2b(acc[i][0]); ov.y = f2b(acc[i][1]);
    ov.z = f2b(acc[i][2]); ov.w = f2b(acc[i][3]);
    *(ushort4*)&hb[(size_t)n * H + c0] = ov;
  }
}

// ---------------- fused lin2+lin (+next-layer lin1): ----------------
// x = xin + silu(A@W2+b2)@W3 + b3 -> xout;  if l1Wn: hb = x@l1Wn (bf16)
__global__ __launch_bounds__(256) void k_gemmF2(
    const float* __restrict__ A, const float* __restrict__ W2,
    const float* __restrict__ b2, const float* __restrict__ W3,
    const float* __restrict__ b3, const float* __restrict__ xin,
    float* __restrict__ xout, const float* __restrict__ l1Wn,
    u16* __restrict__ hb)
{
  __shared__ float sA[32][132];
  __shared__ float sT[32][132];
  int tid = threadIdx.x;
  int n0 = blockIdx.x * 32;
  #pragma unroll
  for (int j = 0; j < 4; ++j) {
    int f4 = tid + j * 256;
    int r = f4 >> 5, c4 = f4 & 31;
    *(float4*)&sA[r][c4 * 4] = *(const float4*)&A[(size_t)(n0 + r) * H + c4 * 4];
  }
  __syncthreads();
  int g = tid >> 5;
  int c0 = (tid & 31) * 4;
  int eb = g * 4;
  float acc[4][4];
  #pragma unroll
  for (int i = 0; i < 4; ++i)
    for (int j = 0; j < 4; ++j) acc[i][j] = 0.f;
  for (int k = 0; k < H; ++k) {
    float4 wv = *(const float4*)&W2[(size_t)k * H + c0];
    #pragma unroll
    for (int i = 0; i < 4; ++i) {
      float a = sA[eb + i][k];
      acc[i][0] += a * wv.x; acc[i][1] += a * wv.y;
      acc[i][2] += a * wv.z; acc[i][3] += a * wv.w;
    }
  }
  float4 bv2 = *(const float4*)&b2[c0];
  #pragma unroll
  for (int i = 0; i < 4; ++i) {
    float t0 = acc[i][0] + bv2.x, t1 = acc[i][1] + bv2.y;
    float t2 = acc[i][2] + bv2.z, t3 = acc[i][3] + bv2.w;
    sT[eb + i][c0 + 0] = t0 / (1.f + __expf(-t0));
    sT[eb + i][c0 + 1] = t1 / (1.f + __expf(-t1));
    sT[eb + i][c0 + 2] = t2 / (1.f + __expf(-t2));
    sT[eb + i][c0 + 3] = t3 / (1.f + __expf(-t3));
  }
  __syncthreads();
  #pragma unroll
  for (int i = 0; i < 4; ++i)
    for (int j = 0; j < 4; ++j) acc[i][j] = 0.f;
  for (int k = 0; k < H; ++k) {
    float4 wv = *(const float4*)&W3[(size_t)k * H + c0];
    #pragma unroll
    for (int i = 0; i < 4; ++i) {
      float a = sT[eb + i][k];
      acc[i][0] += a * wv.x; acc[i][1] += a * wv.y;
      acc[i][2] += a * wv.z; acc[i][3] += a * wv.w;
    }
  }
  float4 bv3 = *(const float4*)&b3[c0];
  #pragma unroll
  for (int i = 0; i < 4; ++i) {
    int n = n0 + eb + i;
    float4 xv = *(const float4*)&xin[(size_t)n * H + c0];
    float o0 = xv.x + acc[i][0] + bv3.x, o1 = xv.y + acc[i][1] + bv3.y;
    float o2 = xv.z + acc[i][2] + bv3.z, o3 = xv.w + acc[i][3] + bv3.w;
    *(float4*)&xout[(size_t)n * H + c0] = make_float4(o0, o1, o2, o3);
    sA[eb + i][c0] = o0; sA[eb + i][c0+1] = o1;
    sA[eb + i][c0+2] = o2; sA[eb + i][c0+3] = o3;
  }
  if (l1Wn) {
    __syncthreads();
    #pragma unroll
    for (int i = 0; i < 4; ++i)
      for (int j = 0; j < 4; ++j) acc[i][j] = 0.f;
    for (int k = 0; k < H; ++k) {
      float4 wv = *(const float4*)&l1Wn[(size_t)k * H + c0];
      #pragma unroll
      for (int i = 0; i < 4; ++i) {
        float a = sA[eb + i][k];
        acc[i][0] += a * wv.x; acc[i][1] += a * wv.y;
        acc[i][2] += a * wv.z; acc[i][3] += a * wv.w;
      }
    }
    #pragma unroll
    for (int i = 0; i < 4; ++i) {
      int n = n0 + eb + i;
      ushort4 ov;
      ov.x = f2b(acc[i][0]); ov.y = f2b(acc[i][1]);
      ov.z = f2b(acc[i][2]); ov.w = f2b(acc[i][3]);
      *(ushort4*)&hb[(size_t)n * H + c0] = ov;
    }
  }
}

// ---------------- barrier-free MFMA neighbor embedding ----------------
__global__ __launch_bounds__(256) void k_nbr2(
    const int* __restrict__ srcS, const int* __restrict__ dstS,
    const float* __restrict__ CS, const u16* __restrict__ attrG,
    const u16* __restrict__ npWt, const float* __restrict__ npb,
    const u16* __restrict__ xnb, float* __restrict__ agg)
{
  __shared__ __align__(16) u16 s_h[128 * 72];
  int tid = threadIdx.x;
  int lane = tid & 63, wv = tid >> 6;
  int r16 = lane & 15, g4 = lane >> 4;
  long base = (long)blockIdx.x * 128 + wv * 32;
  int wrow = wv * 32;
  int e32 = lane & 31;
  int srcR = srcS[base + e32];
  int dstR = dstS[base + e32];
  float CR = CS[base + e32];
  short8v hpA[4];
  {
    int s = __shfl(srcR, lane >> 2, 64);
    const u16* p = xnb + (size_t)s * H + (lane & 3) * 32;
    #pragma unroll
    for (int j = 0; j < 4; ++j) hpA[j] = *(const short8v*)(p + 8*j);
  }
  f32x4 acc[2][8];
  #pragma unroll
  for (int rl = 0; rl < 2; ++rl)
    for (int ct = 0; ct < 8; ++ct) acc[rl][ct] = (f32x4){0.f,0.f,0.f,0.f};
  #pragma unroll
  for (int kt = 0; kt < 2; ++kt) {
    short8v aF[2];
    #pragma unroll
    for (int rl = 0; rl < 2; ++rl)
      aF[rl] = *(const short8v*)&attrG[(base + rl*16 + r16) * 64 + kt*32 + g4*8];
    #pragma unroll
    for (int ct = 0; ct < 8; ++ct) {
      short8v bF = *(const short8v*)&npWt[(ct*16 + r16) * 64 + kt*32 + g4*8];
      #pragma unroll
      for (int rl = 0; rl < 2; ++rl)
        acc[rl][ct] = __builtin_amdgcn_mfma_f32_16x16x32_bf16(aF[rl], bF, acc[rl][ct], 0, 0, 0);
    }
  }
  short8v hpB[4];
  {
    int s = __shfl(srcR, 16 + (lane >> 2), 64);
    const u16* p = xnb + (size_t)s * H + (lane & 3) * 32;
    #pragma unroll
    for (int j = 0; j < 4; ++j) hpB[j] = *(const short8v*)(p + 8*j);
  }
  float bb[8];
  #pragma unroll
  for (int ct = 0; ct < 8; ++ct) bb[ct] = npb[ct*16 + r16];
  float vsum[8];
  int pdst = -1;
  #pragma unroll
  for (int rl = 0; rl < 2; ++rl) {
    {
      int q = lane & 3;
      int row = wrow + 2*(lane >> 2) + (q >> 1);
      u16* d = &s_h[row * 72 + (q & 1) * 32];
      #pragma unroll
      for (int j = 0; j < 4; ++j) *(short8v*)(d + 8*j) = (rl ? hpB[j] : hpA[j]);
    }
    int d0  = __shfl(dstR, rl*16, 64);
    int d15 = __shfl(dstR, rl*16 + 15, 64);
    if (d0 == d15) {
      float part[8];
      #pragma unroll
      for (int ct = 0; ct < 8; ++ct) part[ct] = 0.f;
      #pragma unroll
      for (int r = 0; r < 4; ++r) {
        int el = g4*4 + r;
        float Ce = __shfl(CR, rl*16 + el, 64);
        int se = __shfl(srcR, rl*16 + el, 64);
        float m = (se != d0) ? Ce : 0.f;
        #pragma unroll
        for (int ct = 0; ct < 8; ++ct) {
          float hv = b2f(s_h[(wrow + 2*el + (ct>>2)) * 72 + (ct&3)*16 + r16]);
          part[ct] += (acc[rl][ct][r] + bb[ct]) * m * hv;
        }
      }
      #pragma unroll
      for (int ct = 0; ct < 8; ++ct) {
        part[ct] += __shfl_xor(part[ct], 16, 64);
        part[ct] += __shfl_xor(part[ct], 32, 64);
      }
      if (g4 == 0) {
        if (d0 != pdst) {
          if (pdst >= 0) {
            float* ap = agg + (size_t)pdst * H + r16;
            #pragma unroll
            for (int ct = 0; ct < 8; ++ct) atomicAdd(ap + ct*16, vsum[ct]);
          }
          #pragma unroll
          for (int ct = 0; ct < 8; ++ct) vsum[ct] = 0.f;
          pdst = d0;
        }
        #pragma unroll
        for (int ct = 0; ct < 8; ++ct) vsum[ct] += part[ct];
      }
    } else {
      #pragma unroll
      for (int r = 0; r < 4; ++r) {
        int el = g4*4 + r;
        int dn = __shfl(dstR, rl*16 + el, 64);
        float Ce = __shfl(CR, rl*16 + el, 64);
        int se = __shfl(srcR, rl*16 + el, 64);
        float m = (se != dn) ? Ce : 0.f;
        if (dn != pdst) {
          if (pdst >= 0) {
            float* ap = agg + (size_t)pdst * H + r16;
            #pragma unroll
            for (int ct = 0; ct < 8; ++ct) atomicAdd(ap + ct*16, vsum[ct]);
          }
          #pragma unroll
          for (int ct = 0; ct < 8; ++ct) vsum[ct] = 0.f;
          pdst = dn;
        }
        #pragma unroll
        for (int ct = 0; ct < 8; ++ct) {
          float hv = b2f(s_h[(wrow + 2*el + (ct>>2)) * 72 + (ct&3)*16 + r16]);
          vsum[ct] += (acc[rl][ct][r] + bb[ct]) * m * hv;
        }
      }
    }
  }
  if (pdst >= 0) {
    float* ap = agg + (size_t)pdst * H + r16;
    #pragma unroll
    for (int ct = 0; ct < 8; ++ct) atomicAdd(ap + ct*16, vsum[ct]);
  }
}

// ---------------- barrier-free MFMA CFConv (K-split GEMM2) ----------------
__global__ __launch_bounds__(256) void k_cf2(
    const int* __restrict__ srcS, const int* __restrict__ dstS,
    const float* __restrict__ CS, const u16* __restrict__ attrG,
    const u16* __restrict__ w1t, const float* __restrict__ b1,
    const u16* __restrict__ w2t, const float* __restrict__ b2,
    const u16* __restrict__ h, float* __restrict__ agg)
{
  __shared__ __align__(16) u16 s_t1[128 * 72];   // t1 halves, then h staging
  int tid = threadIdx.x;
  int lane = tid & 63, wv = tid >> 6;
  int r16 = lane & 15, g4 = lane >> 4;
  long base = (long)blockIdx.x * 128 + wv * 32;
  int wrow = wv * 32;
  int e32 = lane & 31;
  int srcR = srcS[base + e32];
  int dstR = dstS[base + e32];
  float CR = CS[base + e32];
  // prefetch band A h rows
  short8v hpA[4];
  {
    int s = __shfl(srcR, lane >> 2, 64);
    const u16* p = h + (size_t)s * H + (lane & 3) * 32;
    #pragma unroll
    for (int j = 0; j < 4; ++j) hpA[j] = *(const short8v*)(p + 8*j);
  }
  // GEMM1: attr @ W1t
  f32x4 acc1[2][8];
  #pragma unroll
  for (int rl = 0; rl < 2; ++rl)
    for (int ct = 0; ct < 8; ++ct) acc1[rl][ct] = (f32x4){0.f,0.f,0.f,0.f};
  #pragma unroll
  for (int kt = 0; kt < 2; ++kt) {
    short8v aF[2];
    #pragma unroll
    for (int rl = 0; rl < 2; ++rl)
      aF[rl] = *(const short8v*)&attrG[(base + rl*16 + r16) * 64 + kt*32 + g4*8];
    #pragma unroll
    for (int ct = 0; ct < 8; ++ct) {
      short8v bF = *(const short8v*)&w1t[(ct*16 + r16) * 64 + kt*32 + g4*8];
      #pragma unroll
      for (int rl = 0; rl < 2; ++rl)
        acc1[rl][ct] = __builtin_amdgcn_mfma_f32_16x16x32_bf16(aF[rl], bF, acc1[rl][ct], 0, 0, 0);
    }
  }
  // prefetch band B h rows (hides under silu+GEMM2)
  short8v hpB[4];
  {
    int s = __shfl(srcR, 16 + (lane >> 2), 64);
    const u16* p = h + (size_t)s * H + (lane & 3) * 32;
    #pragma unroll
    for (int j = 0; j < 4; ++j) hpB[j] = *(const short8v*)(p + 8*j);
  }
  // K-split GEMM2: per half, silu 4 ct-tiles into [128][72] then consume
  f32x4 acc2[2][8];
  #pragma unroll
  for (int rl = 0; rl < 2; ++rl)
    for (int ct = 0; ct < 8; ++ct) acc2[rl][ct] = (f32x4){0.f,0.f,0.f,0.f};
  #pragma unroll
  for (int half = 0; half < 2; ++half) {
    #pragma unroll
    for (int ct4 = 0; ct4 < 4; ++ct4) {
      int ct = half*4 + ct4;
      float bbv = b1[ct*16 + r16];
      #pragma unroll
      for (int rl = 0; rl < 2; ++rl) {
        int rbase = wrow + rl*16 + g4*4;
        #pragma unroll
        for (int r = 0; r < 4; ++r) {
          float v = acc1[rl][ct][r] + bbv;
          v = v / (1.f + __expf(-v));
          s_t1[(rbase + r) * 72 + ct4*16 + r16] = f2b(v);
        }
      }
    }
    #pragma unroll
    for (int kt2 = 0; kt2 < 2; ++kt2) {
      short8v aF[2];
      #pragma unroll
      for (int rl = 0; rl < 2; ++rl)
        aF[rl] = *(const short8v*)&s_t1[(wrow + rl*16 + r16) * 72 + kt2*32 + g4*8];
      #pragma unroll
      for (int ct = 0; ct < 8; ++ct) {
        short8v bF = *(const short8v*)&w2t[(ct*16 + r16) * 136 + half*64 + kt2*32 + g4*8];
        #pragma unroll
        for (int rl = 0; rl < 2; ++rl)
          acc2[rl][ct] = __builtin_amdgcn_mfma_f32_16x16x32_bf16(aF[rl], bF, acc2[rl][ct], 0, 0, 0);
      }
    }
  }
  // epilogue per band: stage h rows into dead t1 region, run-merge atomics
  float bb2[8];
  #pragma unroll
  for (int ct = 0; ct < 8; ++ct) bb2[ct] = b2[ct*16 + r16];
  float vsum[8];
  int pdst = -1;
  #pragma unroll
  for (int rl = 0; rl < 2; ++rl) {
    {
      int q = lane & 3;
      int row = wrow + 2*(lane >> 2) + (q >> 1);
      u16* d = &s_t1[row * 72 + (q & 1) * 32];
      #pragma unroll
      for (int j = 0; j < 4; ++j) *(short8v*)(d + 8*j) = (rl ? hpB[j] : hpA[j]);
    }
    int d0  = __shfl(dstR, rl*16, 64);
    int d15 = __shfl(dstR, rl*16 + 15, 64);
    if (d0 == d15) {
      float part[8];
      #pragma unroll
      for (int ct = 0; ct < 8; ++ct) part[ct] = 0.f;
      #pragma unroll
      for (int r = 0; r < 4; ++r) {
        int el = g4*4 + r;
        float Ce = __shfl(CR, rl*16 + el, 64);
        #pragma unroll
        for (int ct = 0; ct < 8; ++ct) {
          float hv = b2f(s_t1[(wrow + 2*el + (ct>>2)) * 72 + (ct&3)*16 + r16]);
          part[ct] += (acc2[rl][ct][r] + bb2[ct]) * Ce * hv;
        }
      }
      #pragma unroll
      for (int ct = 0; ct < 8; ++ct) {
        part[ct] += __shfl_xor(part[ct], 16, 64);
        part[ct] += __shfl_xor(part[ct], 32, 64);
      }
      if (g4 == 0) {
        if (d0 != pdst) {
          if (pdst >= 0) {
            float* ap = agg + (size_t)pdst * H + r16;
            #pragma unroll
            for (int ct = 0; ct < 8; ++ct) atomicAdd(ap + ct*16, vsum[ct]);
          }
          #pragma unroll
          for (int ct = 0; ct < 8; ++ct) vsum[ct] = 0.f;
          pdst = d0;
        }
        #pragma unroll
        for (int ct = 0; ct < 8; ++ct) vsum[ct] += part[ct];
      }
    } else {
      #pragma unroll
      for (int r = 0; r < 4; ++r) {
        int el = g4*4 + r;
        int dn = __shfl(dstR, rl*16 + el, 64);
        float Ce = __shfl(CR, rl*16 + el, 64);
        if (dn != pdst) {
          if (pdst >= 0) {
            float* ap = agg + (size_t)pdst * H + r16;
            #pragma unroll
            for (int ct = 0; ct < 8; ++ct) atomicAdd(ap + ct*16, vsum[ct]);
          }
          #pragma unroll
          for (int ct = 0; ct < 8; ++ct) vsum[ct] = 0.f;
          pdst = dn;
        }
        #pragma unroll
        for (int ct = 0; ct < 8; ++ct) {
          float hv = b2f(s_t1[(wrow + 2*el + (ct>>2)) * 72 + (ct&3)*16 + r16]);
          vsum[ct] += (acc2[rl][ct][r] + bb2[ct]) * Ce * hv;
        }
      }
    }
  }
  if (pdst >= 0) {
    float* ap = agg + (size_t)pdst * H + r16;
    #pragma unroll
    for (int ct = 0; ct < 8; ++ct) atomicAdd(ap + ct*16, vsum[ct]);
  }
}

// ---------------- launcher ----------------
extern "C" void kernel_launch(void* const* d_in, const int* in_sizes, int n_in,
                              void* d_out, int out_size, void* d_ws, size_t ws_size,
                              hipStream_t stream) {
  int bo = (n_in >= 4 && in_sizes[3] == NN) ? 0 : -1;  // batch present?
  const int*   z     = (const int*)d_in[0];
  const float* pos   = (const float*)d_in[1];
  const int*   ei    = (const int*)d_in[2];
  const float* emb   = (const float*)d_in[4 + bo];
  const float* nemb  = (const float*)d_in[5 + bo];
  const float* npW   = (const float*)d_in[6 + bo];
  const float* npb   = (const float*)d_in[7 + bo];
  const float* cW    = (const float*)d_in[8 + bo];
  const float* cb    = (const float*)d_in[9 + bo];
  const float* means = (const float*)d_in[10 + bo];
  const float* betas = (const float*)d_in[11 + bo];
  const float* W1    = (const float*)d_in[12 + bo];
  const float* b1    = (const float*)d_in[13 + bo];
  const float* W2    = (const float*)d_in[14 + bo];
  const float* b2    = (const float*)d_in[15 + bo];
  const float* l1W   = (const float*)d_in[16 + bo];
  const float* l2W   = (const float*)d_in[17 + bo];
  const float* l2b   = (const float*)d_in[18 + bo];
  const float* lW    = (const float*)d_in[19 + bo];
  const float* lb    = (const float*)d_in[20 + bo];

  char* w = (char*)d_ws;
  auto alloc = [&](size_t bytes) { char* p = w; w += (bytes + 255) & ~(size_t)255; return p; };
  int*   counts = (int*)  alloc((size_t)NN * 4);
  int*   cursor = (int*)  alloc((size_t)NN * 4);
  int*   perm   = (int*)  alloc((size_t)NE * 4);
  int*   srcS   = (int*)  alloc((size_t)NE * 4);
  int*   dstS   = (int*)  alloc((size_t)NE * 4);
  float* CS     = (float*)alloc((size_t)NE * 4);
  u16*   attrG  = (u16*)  alloc((size_t)NE * 64 * 2);
  u16*   npWt   = (u16*)  alloc((size_t)128 * 64 * 2);
  u16*   w1tA   = (u16*)  alloc((size_t)NL * 128 * 64 * 2);
  u16*   w2tA   = (u16*)  alloc((size_t)NL * 128 * 136 * 2);
  float* xbuf   = (float*)alloc((size_t)NN * H * 4);
  float* agg    = (float*)alloc((size_t)NN * H * 4);
  u16*   xnb    = (u16*)  alloc((size_t)NN * H * 2);
  u16*   hbuf   = (u16*)  alloc((size_t)NN * H * 2);

  dim3 b256(256);
  int gE256 = (NE + 255) / 256;        // 2500
  int gNH   = (NN * H + 255) / 256;    // 10000
  int gCF   = NE / 128;                // 5000
  int gG    = NN / 32;                 // 625

  k_zero_i32<<<(NN + 255) / 256, b256, 0, stream>>>(counts, NN);
  k_hist<<<gE256, b256, 0, stream>>>(ei, counts);
  k_scan<<<1, 1024, 0, stream>>>(counts, cursor);
  k_place<<<gE256, b256, 0, stream>>>(ei, cursor, perm);
  k_edge<<<gE256, b256, 0, stream>>>(ei, perm, pos, means, betas, srcS, dstS, CS, attrG);
  k_prepw<<<(161792 + 255) / 256, b256, 0, stream>>>(npW, W1, W2, npWt, w1tA, w2tA);
  k_embed<<<gNH, b256, 0, stream>>>(z, emb, nemb, xbuf, xnb);

  // neighbor embedding (agg in workspace; xbuf holds x)
  k_zero_f32<<<gNH, b256, 0, stream>>>(agg, NN * H);
  k_nbr2<<<gCF, b256, 0, stream>>>(srcS, dstS, CS, attrG, npWt, npb, xnb, agg);

  // combine + layer-0 lin1
  k_combine<<<gG, b256, 0, stream>>>(xbuf, agg, cW, cb, l1W, xbuf, hbuf);

  for (int l = 0; l < NL; ++l) {
    k_zero_f32<<<gNH, b256, 0, stream>>>(agg, NN * H);
    k_cf2<<<gCF, b256, 0, stream>>>(srcS, dstS, CS, attrG,
                                    w1tA + (size_t)l * 128 * 64, b1 + (size_t)l * H,
                                    w2tA + (size_t)l * 128 * 136, b2 + (size_t)l * H,
                                    hbuf, agg);
    const float* l1Wn = (l + 1 < NL) ? (l1W + (size_t)(l + 1) * H * H) : nullptr;
    float* xo = (l == NL - 1) ? (float*)d_out : xbuf;
    k_gemmF2<<<gG, b256, 0, stream>>>(agg, l2W + (size_t)l * H * H, l2b + (size_t)l * H,
                                      lW + (size_t)l * H * H, lb + (size_t)l * H,
                                      xbuf, xo, l1Wn, hbuf);
  }
}